// Round 1
// 109.993 us; speedup vs baseline: 1.0377x; 1.0377x over previous
//
#include <hip/hip_runtime.h>

#define NQ 14
#define NSTATE (1 << NQ)       // 16384 amplitudes
#define NL 3
#define MAXP 12                // max passes (fallback layer-local packing)
#define BT 1024                // threads per block
#define NWAVES (BT / 64)

// Lazily-permuted simulation: CNOT rings folded into GF(2) index maps, and a
// global GF(2)-linear LDS layout sigma (amp p stored at address sigma(p)).
// sigma is chosen host-side so that EVERY pass's representative space
// projects with full rank 4 onto the bank-pair bits (addr mod 16).
// New in this version:
//  - greedy cross-layer gate packing -> 11 passes instead of 12
//  - pass 0 fused with |0> init (no reads; only thread 0 does gate math)
//  - measurement fused into the final pass (no final write/barrier/re-read)
//  - rep value r software-pipelined one pass ahead (off the post-barrier path)
struct PassP {
    unsigned short R[10];
    unsigned short cmb[16];
    unsigned char gidx[4];
    unsigned char nw;
    unsigned char _pad;
};
struct SimParams {
    PassP pass[MAXP];
    unsigned short ms[NQ];     // Z_w selector masks, address space (14-bit)
    unsigned short fmask[NQ];  // bit i = par(cmb_last[i] & ms[w])
    int np;                    // actual pass count (<= MAXP)
};

struct C2x2 { float2 m[2][2]; };

__device__ __forceinline__ float2 cmul(float2 a, float2 b) {
    return make_float2(a.x * b.x - a.y * b.y, a.x * b.y + a.y * b.x);
}
__device__ __forceinline__ float2 cmac(float2 acc, float2 a, float2 b) {
    acc.x = fmaf(a.x, b.x, fmaf(-a.y, b.y, acc.x));
    acc.y = fmaf(a.x, b.y, fmaf(a.y, b.x, acc.y));
    return acc;
}

// PennyLane Rot(phi,theta,omega) = RZ(omega) RY(theta) RZ(phi)
__device__ __forceinline__ C2x2 rot_gate(const float* qp) {
    float phi = qp[0], th = qp[1], om = qp[2];
    float ct, stt; __sincosf(0.5f * th, &stt, &ct);
    float sa, ca; __sincosf(0.5f * (phi + om), &sa, &ca);
    float sb, cb; __sincosf(0.5f * (phi - om), &sb, &cb);
    C2x2 G;
    G.m[0][0] = make_float2(ca * ct, -sa * ct);
    G.m[0][1] = make_float2(-cb * stt, -sb * stt);
    G.m[1][0] = make_float2(cb * stt, -sb * stt);
    G.m[1][1] = make_float2(ca * ct, sa * ct);
    return G;
}

// G := G * RX(ang)   (RX applied first to the state)
__device__ __forceinline__ C2x2 fuse_rx(C2x2 G, float ang) {
    float sh, ch; __sincosf(0.5f * ang, &sh, &ch);
    float2 c = make_float2(ch, 0.f), is = make_float2(0.f, -sh);
    C2x2 R;
    #pragma unroll
    for (int i = 0; i < 2; ++i) {
        R.m[i][0] = cmac(cmul(G.m[i][0], c), G.m[i][1], is);
        R.m[i][1] = cmac(cmul(G.m[i][1], c), G.m[i][0], is);
    }
    return R;
}

// staged 2x2 gate applications on a[16]; a[] indexed by logical bits
#define APPLY_STAGES(PSIDX)                                                 \
    {                                                                       \
        const int nw_ = P.pass[PSIDX].nw;                                   \
        _Pragma("unroll")                                                   \
        for (int q = 0; q < 4; ++q) {                                       \
            if (q < nw_) {    /* wave-uniform branch */                     \
                const int gi = (int)P.pass[PSIDX].gidx[q] * 4;              \
                float2 g00 = gbuf[gi + 0], g01 = gbuf[gi + 1];              \
                float2 g10 = gbuf[gi + 2], g11 = gbuf[gi + 3];              \
                _Pragma("unroll")                                           \
                for (int i = 0; i < 16; ++i) {                              \
                    if (!((i >> q) & 1)) {                                  \
                        const int i1 = i | (1 << q);                        \
                        float2 a0 = a[i], a1 = a[i1];                       \
                        float2 n0 = cmac(cmul(g00, a0), g01, a1);           \
                        float2 n1 = cmac(cmul(g10, a0), g11, a1);           \
                        a[i] = n0; a[i1] = n1;                              \
                    }                                                       \
                }                                                           \
            }                                                               \
        }                                                                   \
    }

__global__ __launch_bounds__(BT) void qsim_kernel(
    const float* __restrict__ x, const float* __restrict__ qw,
    const float* __restrict__ wl, const float* __restrict__ bl,
    float* __restrict__ out, SimParams P)
{
    __shared__ float2 st[NSTATE];          // 128 KB state
    __shared__ float2 gbuf[NL * NQ * 4];   // 42 precomputed 2x2 gates
    __shared__ float red[NWAVES];

    const int tid = threadIdx.x;
    const int b = blockIdx.x;

    // precompute all 2x2 gates once (layer 0 fuses the RX embedding)
    if (tid < NL * NQ) {
        int l = tid / NQ, w = tid % NQ;
        C2x2 G = rot_gate(qw + tid * 3);
        if (l == 0) G = fuse_rx(G, x[b * NQ + w]);
        gbuf[tid * 4 + 0] = G.m[0][0];
        gbuf[tid * 4 + 1] = G.m[0][1];
        gbuf[tid * 4 + 2] = G.m[1][0];
        gbuf[tid * 4 + 3] = G.m[1][1];
    }

    const int np = P.np;
    char* sb = (char*)st;
    float2 a[16];
    unsigned addr[16];

    // rep value for pass 0 (GF(2)-linear in tid)
    unsigned r0 = 0;
    #pragma unroll
    for (int j = 0; j < 10; ++j)
        r0 ^= ((tid >> j) & 1) ? (unsigned)P.pass[0].R[j] : 0u;

    __syncthreads();   // gbuf ready

    // ---- pass 0: fused |0>-init, no reads ----
    {
        const unsigned rb = r0 << 3;
        #pragma unroll
        for (int i = 0; i < 16; ++i)
            addr[i] = rb ^ (((unsigned)P.pass[0].cmb[i]) << 3);
        #pragma unroll
        for (int i = 0; i < 16; ++i) a[i] = make_float2(0.f, 0.f);
        if (tid == 0) {            // only group containing index 0 is nonzero
            a[0] = make_float2(1.f, 0.f);
            APPLY_STAGES(0);
        }
        #pragma unroll
        for (int i = 0; i < 16; ++i)
            *(float2*)(sb + addr[i]) = a[i];   // this IS the state init
    }

    // pipeline: rep value for pass 1
    unsigned rn = 0;
    #pragma unroll
    for (int j = 0; j < 10; ++j)
        rn ^= ((tid >> j) & 1) ? (unsigned)P.pass[1].R[j] : 0u;

    #pragma unroll 1
    for (int ps = 1; ps < np - 1; ++ps) {
        __syncthreads();   // previous pass's writes visible
        const unsigned rb = rn << 3;
        #pragma unroll
        for (int i = 0; i < 16; ++i)
            addr[i] = rb ^ (((unsigned)P.pass[ps].cmb[i]) << 3);
        #pragma unroll
        for (int i = 0; i < 16; ++i)
            a[i] = *(const float2*)(sb + addr[i]);
        // compute next pass's rep during this pass's compute (off crit path)
        unsigned rt = 0;
        #pragma unroll
        for (int j = 0; j < 10; ++j)
            rt ^= ((tid >> j) & 1) ? (unsigned)P.pass[ps + 1].R[j] : 0u;
        APPLY_STAGES(ps);
        rn = rt;
        #pragma unroll
        for (int i = 0; i < 16; ++i)
            *(float2*)(sb + addr[i]) = a[i];
    }

    // ---- final pass: reads + gates, measurement straight from registers ----
    float acc = 0.f;
    {
        const int ps = np - 1;
        __syncthreads();
        const unsigned rb = rn << 3;
        #pragma unroll
        for (int i = 0; i < 16; ++i)
            addr[i] = rb ^ (((unsigned)P.pass[ps].cmb[i]) << 3);
        #pragma unroll
        for (int i = 0; i < 16; ++i)
            a[i] = *(const float2*)(sb + addr[i]);
        APPLY_STAGES(ps);

        // weight of amp at address rn^cmb_i: sign_w = par(rn&ms_w) ^ fmask_w[i]
        float A[16];
        #pragma unroll
        for (int i = 0; i < 16; ++i) A[i] = 0.f;
        #pragma unroll
        for (int w = 0; w < NQ; ++w) {
            float v = wl[w];
            unsigned p0 = __popc(rn & (unsigned)P.ms[w]) & 1u;
            float vs = p0 ? -v : v;
            const unsigned fm = (unsigned)P.fmask[w];
            #pragma unroll
            for (int i = 0; i < 16; ++i)
                A[i] += ((fm >> i) & 1u) ? -vs : vs;
        }
        #pragma unroll
        for (int i = 0; i < 16; ++i)
            acc = fmaf(fmaf(a[i].x, a[i].x, a[i].y * a[i].y), A[i], acc);
    }

    #pragma unroll
    for (int off = 32; off > 0; off >>= 1) acc += __shfl_down(acc, off, 64);
    if ((tid & 63) == 0) red[tid >> 6] = acc;
    __syncthreads();
    if (tid == 0) {
        float s2 = 0.f;
        #pragma unroll
        for (int i = 0; i < NWAVES; ++i) s2 += red[i];
        out[b] = s2 + bl[0];
    }
}

// ---- host-side GF(2) helpers ----
struct GF2Basis {
    unsigned piv[NQ];
    GF2Basis() { for (int i = 0; i < NQ; ++i) piv[i] = 0; }
    bool insert(unsigned v) {            // true iff rank increased
        for (int bb = NQ - 1; bb >= 0; --bb) {
            if (!((v >> bb) & 1)) continue;
            if (piv[bb]) v ^= piv[bb];
            else { piv[bb] = v; return true; }
        }
        return false;
    }
};

static inline int par16(unsigned v) { return __builtin_parity(v); }
static inline unsigned lcg_next(unsigned& s) { s = s * 1664525u + 1013904223u; return s >> 8; }

static unsigned gf_apply(const unsigned* C, unsigned v) {
    unsigned r = 0;
    while (v) { int j = __builtin_ctz(v); v &= v - 1; r ^= C[j]; }
    return r;
}

// C = columns of sigma; on success Ci = columns of sigma^{-1}
static bool gf_invert(const unsigned* C, unsigned* Ci) {
    unsigned rows[NQ], irows[NQ];
    for (int i = 0; i < NQ; ++i) {
        unsigned r = 0;
        for (int j = 0; j < NQ; ++j) r |= ((C[j] >> i) & 1u) << j;
        rows[i] = r; irows[i] = 1u << i;
    }
    for (int c = 0; c < NQ; ++c) {
        int p = -1;
        for (int r = c; r < NQ; ++r) if ((rows[r] >> c) & 1u) { p = r; break; }
        if (p < 0) return false;
        unsigned t = rows[p]; rows[p] = rows[c]; rows[c] = t;
        t = irows[p]; irows[p] = irows[c]; irows[c] = t;
        for (int r = 0; r < NQ; ++r)
            if (r != c && ((rows[r] >> c) & 1u)) { rows[r] ^= rows[c]; irows[r] ^= irows[c]; }
    }
    for (int j = 0; j < NQ; ++j) {
        unsigned col = 0;
        for (int i = 0; i < NQ; ++i) col |= ((irows[i] >> j) & 1u) << i;
        Ci[j] = col;
    }
    return true;
}

extern "C" void kernel_launch(void* const* d_in, const int* in_sizes, int n_in,
                              void* d_out, int out_size, void* d_ws, size_t ws_size,
                              hipStream_t stream) {
    const float* x  = (const float*)d_in[0];   // (B, 14)
    const float* qw = (const float*)d_in[1];   // (3, 14, 3)
    const float* wl = (const float*)d_in[2];   // (1, 14)
    const float* bl = (const float*)d_in[3];   // (1,)
    float* out = (float*)d_out;                // (B, 1)

    const int B = in_sizes[0] / NQ;

    // ---- build gate list in circuit order with (s,m) captured per gate ----
    // s[w] = selector row, m[w] = flip mask; par(s_i & m_j)=delta_ij at all
    // times (ring updates preserve duality of the CURRENT frame).
    unsigned gs[NL * NQ], gm[NL * NQ];
    int ggi[NL * NQ];
    unsigned s[NQ], m[NQ], msIdx[NQ];
    for (int w = 0; w < NQ; ++w) s[w] = m[w] = 1u << (NQ - 1 - w); // wire 0 = MSB
    int ng = 0;
    for (int l = 0; l < NL; ++l) {
        for (int w = 0; w < NQ; ++w) {
            gs[ng] = s[w]; gm[ng] = m[w]; ggi[ng] = l * NQ + w; ++ng;
        }
        int r = (l % (NQ - 1)) + 1;            // PennyLane ranges: 1,2,3
        for (int w = 0; w < NQ; ++w) {         // CNOT ring: control w, target (w+r)%NQ
            int c = w, t = (w + r) % NQ;
            s[t] ^= s[c];
            m[c] ^= m[t];
        }
    }
    for (int w = 0; w < NQ; ++w) msIdx[w] = s[w];

    // ---- greedy pack gates into passes (cross-layer mixing allowed) ----
    // A gate g may join the current pass iff:
    //  (a) biorthogonal with all pass members: par(s_g&m_k)=par(s_k&m_g)=0
    //  (b) commutes with every earlier-in-circuit, not-yet-applied gate h:
    //      par(s_g&m_h)=par(s_h&m_g)=0  (reordering validity)
    //  (c) m_g independent of the pass's flip-mask span
    // Worst case this degrades to layer-local 4/4/4/2 packing (<=12 passes);
    // for this circuit it yields 11 passes.
    struct Raw { unsigned rv[10], cmb[16]; unsigned char gidx[4], nw; } raw[MAXP];
    bool used[NL * NQ] = {false};
    int np = 0, remaining = ng;
    while (remaining > 0 && np < MAXP) {
        unsigned pss[4], pmm[4];
        int pgi[4], nw = 0;
        GF2Basis gf;
        for (int g = 0; g < ng && nw < 4; ++g) {
            if (used[g]) continue;
            bool ok = true;
            for (int k = 0; k < nw && ok; ++k)
                if (par16(gs[g] & pmm[k]) || par16(pss[k] & gm[g])) ok = false;
            for (int h = 0; h < g && ok; ++h)
                if (!used[h] && (par16(gs[g] & gm[h]) || par16(gs[h] & gm[g]))) ok = false;
            if (!ok) continue;
            GF2Basis trial = gf;
            if (!trial.insert(gm[g])) continue;
            gf = trial;
            pss[nw] = gs[g]; pmm[nw] = gm[g]; pgi[nw] = g; ++nw;
            used[g] = true; --remaining;
        }
        // pad to 4 independent masks; normalize pads so they don't flip the
        // real wires' logical bits
        unsigned mm[4], ss[4];
        for (int i = 0; i < nw; ++i) { mm[i] = pmm[i]; ss[i] = pss[i]; }
        for (int i = nw; i < 4; ++i) {
            unsigned cand = 0;
            for (int t = 0; t < NQ; ++t)
                if (gf.insert(1u << t)) { cand = 1u << t; break; }
            for (int j = 0; j < nw; ++j)
                if (par16(cand & ss[j])) cand ^= mm[j];
            mm[i] = cand; ss[i] = 0;
        }
        // complement basis (10 vecs), normalized to zero logical bits
        int nR = 0;
        for (int t = 0; t < NQ && nR < 10; ++t) {
            if (gf.insert(1u << t)) {
                unsigned v = 1u << t;
                for (int j = 0; j < nw; ++j)
                    if (par16(v & ss[j])) v ^= mm[j];
                raw[np].rv[nR++] = v;
            }
        }
        for (int idx = 0; idx < 16; ++idx) {
            unsigned c = 0;
            for (int q = 0; q < 4; ++q) if ((idx >> q) & 1) c ^= mm[q];
            raw[np].cmb[idx] = c;
        }
        for (int q = 0; q < 4; ++q)
            raw[np].gidx[q] = (unsigned char)(q < nw ? ggi[pgi[q]] : 0);
        raw[np].nw = (unsigned char)nw;
        ++np;
    }

    // ---- choose layout sigma: every pass's rep space must project with
    // rank 4 onto the bank-pair bits (addr mod 16) ----
    unsigned Cm[NQ], Ci[NQ];
    unsigned seed = 0x9E3779B9u;
    bool found = false;
    for (int tries = 0; tries < 5000 && !found; ++tries) {
        for (int j = 0; j < NQ; ++j) Cm[j] = lcg_next(seed) & (NSTATE - 1);
        if (!gf_invert(Cm, Ci)) continue;
        found = true;
        for (int p = 0; p < np && found; ++p) {
            unsigned piv[4] = {0, 0, 0, 0}; int npv = 0;
            for (int i = 0; i < 10; ++i) {
                unsigned w2 = gf_apply(Cm, raw[p].rv[i]);
                for (int bb = 0; bb < 4; ++bb)
                    if (((w2 >> bb) & 1u) && piv[bb]) w2 ^= piv[bb];
                if ((w2 & 15u) && npv < 4) { piv[__builtin_ctz(w2 & 15u)] = w2; ++npv; }
            }
            if (npv < 4) found = false;
        }
    }
    if (!found) {  // fallback: identity layout (correct, just slower)
        for (int j = 0; j < NQ; ++j) Cm[j] = 1u << j;
        gf_invert(Cm, Ci);
    }

    // ---- emit device params in ADDRESS space ----
    SimParams P = {};
    P.np = np;
    for (int p = 0; p < np; ++p) {
        unsigned u[10];
        for (int i = 0; i < 10; ++i) u[i] = gf_apply(Cm, raw[p].rv[i]);
        // order: 4 bank-pivot vectors first (they cover lane bits 0..3)
        unsigned piv[4] = {0, 0, 0, 0};
        int ord[10], npv = 0, rest[10], nrest = 0;
        for (int i = 0; i < 10; ++i) {
            unsigned w2 = u[i];
            for (int bb = 0; bb < 4; ++bb)
                if (((w2 >> bb) & 1u) && piv[bb]) w2 ^= piv[bb];
            if ((w2 & 15u) && npv < 4) { piv[__builtin_ctz(w2 & 15u)] = w2; ord[npv++] = i; }
            else rest[nrest++] = i;
        }
        int kk = 0;
        for (int i = 0; i < npv; ++i) P.pass[p].R[kk++] = (unsigned short)u[ord[i]];
        for (int i = 0; i < nrest; ++i) P.pass[p].R[kk++] = (unsigned short)u[rest[i]];
        for (int idx = 0; idx < 16; ++idx)
            P.pass[p].cmb[idx] = (unsigned short)gf_apply(Cm, raw[p].cmb[idx]);
        for (int q = 0; q < 4; ++q) P.pass[p].gidx[q] = raw[p].gidx[q];
        P.pass[p].nw = raw[p].nw;
        P.pass[p]._pad = 0;
    }
    // measurement masks: par(sigma^{-1}(t) & ms) = par(t & sigma^{-T} ms)
    for (int w = 0; w < NQ; ++w) {
        unsigned msp = 0;
        for (int i = 0; i < NQ; ++i)
            msp |= (unsigned)(par16(Ci[i] & msIdx[w]) & 1) << i;
        P.ms[w] = (unsigned short)msp;
    }
    // combo-part parities of the FINAL pass (measurement runs from registers)
    for (int w = 0; w < NQ; ++w) {
        unsigned fm = 0;
        for (int i = 0; i < 16; ++i)
            fm |= (unsigned)(par16((unsigned)P.pass[np - 1].cmb[i] & (unsigned)P.ms[w]) & 1) << i;
        P.fmask[w] = (unsigned short)fm;
    }

    qsim_kernel<<<dim3(B), dim3(BT), 0, stream>>>(x, qw, wl, bl, out, P);
}

// Round 2
// 109.604 us; speedup vs baseline: 1.0414x; 1.0036x over previous
//
#include <hip/hip_runtime.h>
#include <string.h>

#define NQ 14
#define NSTATE (1 << NQ)       // 16384 amplitudes
#define NL 3
#define MAXP 12                // max passes (fallback layer-local packing)
#define BT 1024                // threads per block
#define NWAVES (BT / 64)

// Lazily-permuted simulation: CNOT rings folded into GF(2) index maps, and a
// global GF(2)-linear LDS layout sigma (amp p stored at address sigma(p)).
// sigma is chosen host-side so that EVERY pass's representative space
// projects with full rank 4 onto the bank-pair bits (addr mod 16).
// This version keeps round-1's algorithmic wins (11 passes via cross-layer
// packing, |0>-init fused into pass 0, measurement fused into the final
// pass, rep pipelining) but moves ALL pass parameters into a global-memory
// table (d_ws) prefetched one pass ahead with vmcnt-domain loads, so the
// K-loop's lgkmcnt traffic is pure in-order DS (no SMEM mixing -> no
// conservative lgkmcnt(0) drains) and nothing is runtime-indexed in kernarg
// (no scratch traffic).
struct PassG {
    unsigned cmb8[16];   // XOR combos of the 4 pair masks, pre-shifted <<3 (byte offsets)
    unsigned R[10];      // complement-basis images (tid -> group representative)
    unsigned gidx[4];    // gate table indices
    unsigned nw;         // real gates in this pass
    unsigned pad;        // -> 32 uints = 128 B per pass
};
struct ParamsG {
    PassG pass[MAXP];
    unsigned ms[NQ];     // final Z_w selector masks (address space)
    unsigned fmask[NQ];  // bit i = par(cmb_last[i] & ms[w])
};

struct C2x2 { float2 m[2][2]; };

__device__ __forceinline__ float2 cmul(float2 a, float2 b) {
    return make_float2(a.x * b.x - a.y * b.y, a.x * b.y + a.y * b.x);
}
__device__ __forceinline__ float2 cmac(float2 acc, float2 a, float2 b) {
    acc.x = fmaf(a.x, b.x, fmaf(-a.y, b.y, acc.x));
    acc.y = fmaf(a.x, b.y, fmaf(a.y, b.x, acc.y));
    return acc;
}

// PennyLane Rot(phi,theta,omega) = RZ(omega) RY(theta) RZ(phi)
__device__ __forceinline__ C2x2 rot_gate(const float* qp) {
    float phi = qp[0], th = qp[1], om = qp[2];
    float ct, stt; __sincosf(0.5f * th, &stt, &ct);
    float sa, ca; __sincosf(0.5f * (phi + om), &sa, &ca);
    float sb, cb; __sincosf(0.5f * (phi - om), &sb, &cb);
    C2x2 G;
    G.m[0][0] = make_float2(ca * ct, -sa * ct);
    G.m[0][1] = make_float2(-cb * stt, -sb * stt);
    G.m[1][0] = make_float2(cb * stt, -sb * stt);
    G.m[1][1] = make_float2(ca * ct, sa * ct);
    return G;
}

// G := G * RX(ang)   (RX applied first to the state)
__device__ __forceinline__ C2x2 fuse_rx(C2x2 G, float ang) {
    float sh, ch; __sincosf(0.5f * ang, &sh, &ch);
    float2 c = make_float2(ch, 0.f), is = make_float2(0.f, -sh);
    C2x2 R;
    #pragma unroll
    for (int i = 0; i < 2; ++i) {
        R.m[i][0] = cmac(cmul(G.m[i][0], c), G.m[i][1], is);
        R.m[i][1] = cmac(cmul(G.m[i][1], c), G.m[i][0], is);
    }
    return R;
}

// load one pass's params into registers (global loads only -> vmcnt domain)
__device__ __forceinline__ void load_pass(const PassG* __restrict__ p, int tid,
        unsigned cmb[16], unsigned gidx[4], unsigned& nw, unsigned& r)
{
    const uint4* c4 = (const uint4*)p->cmb8;
    uint4 u0 = c4[0], u1 = c4[1], u2 = c4[2], u3 = c4[3];
    cmb[0] = u0.x; cmb[1] = u0.y; cmb[2]  = u0.z; cmb[3]  = u0.w;
    cmb[4] = u1.x; cmb[5] = u1.y; cmb[6]  = u1.z; cmb[7]  = u1.w;
    cmb[8] = u2.x; cmb[9] = u2.y; cmb[10] = u2.z; cmb[11] = u2.w;
    cmb[12] = u3.x; cmb[13] = u3.y; cmb[14] = u3.z; cmb[15] = u3.w;
    unsigned rr = 0;
    #pragma unroll
    for (int j = 0; j < 10; ++j)
        rr ^= ((tid >> j) & 1) ? p->R[j] : 0u;
    r = rr;
    #pragma unroll
    for (int q = 0; q < 4; ++q) gidx[q] = p->gidx[q];
    nw = p->nw;
}

// staged 2x2 gate applications on a[16] using register params gidxr/nwr
#define APPLY_STAGES()                                                      \
    {                                                                       \
        _Pragma("unroll")                                                   \
        for (int q = 0; q < 4; ++q) {                                       \
            if (q < (int)nwr) {    /* wave-uniform branch */                \
                const int gi = (int)gidxr[q] * 4;                           \
                float2 g00 = gbuf[gi + 0], g01 = gbuf[gi + 1];              \
                float2 g10 = gbuf[gi + 2], g11 = gbuf[gi + 3];              \
                _Pragma("unroll")                                           \
                for (int i = 0; i < 16; ++i) {                              \
                    if (!((i >> q) & 1)) {                                  \
                        const int i1 = i | (1 << q);                        \
                        float2 a0 = a[i], a1 = a[i1];                       \
                        float2 n0 = cmac(cmul(g00, a0), g01, a1);           \
                        float2 n1 = cmac(cmul(g10, a0), g11, a1);           \
                        a[i] = n0; a[i1] = n1;                              \
                    }                                                       \
                }                                                           \
            }                                                               \
        }                                                                   \
    }

__global__ __launch_bounds__(BT) void qsim_kernel(
    const float* __restrict__ x, const float* __restrict__ qw,
    const float* __restrict__ wl, const float* __restrict__ bl,
    float* __restrict__ out, const ParamsG* __restrict__ pp, int np)
{
    __shared__ float2 st[NSTATE];          // 128 KB state
    __shared__ float2 gbuf[NL * NQ * 4];   // 42 precomputed 2x2 gates
    __shared__ float red[NWAVES];

    const int tid = threadIdx.x;
    const int b = blockIdx.x;

    // precompute all 2x2 gates once (layer 0 fuses the RX embedding)
    if (tid < NL * NQ) {
        int l = tid / NQ, w = tid % NQ;
        C2x2 G = rot_gate(qw + tid * 3);
        if (l == 0) G = fuse_rx(G, x[b * NQ + w]);
        gbuf[tid * 4 + 0] = G.m[0][0];
        gbuf[tid * 4 + 1] = G.m[0][1];
        gbuf[tid * 4 + 2] = G.m[1][0];
        gbuf[tid * 4 + 3] = G.m[1][1];
    }

    char* sb = (char*)st;
    float2 a[16];
    unsigned addr[16];
    unsigned cmbreg[16], gidxr[4], nwr, rn;

    load_pass(&pp->pass[0], tid, cmbreg, gidxr, nwr, rn);

    __syncthreads();   // gbuf ready

    // ---- pass 0: fused |0>-init, no reads ----
    {
        const unsigned rb = rn << 3;
        #pragma unroll
        for (int i = 0; i < 16; ++i) addr[i] = rb ^ cmbreg[i];
        #pragma unroll
        for (int i = 0; i < 16; ++i) a[i] = make_float2(0.f, 0.f);
        if (tid == 0) {            // only group containing index 0 is nonzero
            a[0] = make_float2(1.f, 0.f);
            APPLY_STAGES();
        }
        #pragma unroll
        for (int i = 0; i < 16; ++i)
            *(float2*)(sb + addr[i]) = a[i];   // this IS the state init
    }

    load_pass(&pp->pass[1], tid, cmbreg, gidxr, nwr, rn);

    #pragma unroll 1
    for (int ps = 1; ps < np - 1; ++ps) {
        __syncthreads();   // previous pass's writes visible
        const unsigned rb = rn << 3;
        #pragma unroll
        for (int i = 0; i < 16; ++i) addr[i] = rb ^ cmbreg[i];
        #pragma unroll
        for (int i = 0; i < 16; ++i)
            a[i] = *(const float2*)(sb + addr[i]);
        // prefetch next pass's params during this pass's compute
        // (global loads -> vmcnt, cannot force lgkmcnt drains on the ds_reads)
        unsigned cmbn[16], gidxn[4], nwn, rnn;
        load_pass(&pp->pass[ps + 1], tid, cmbn, gidxn, nwn, rnn);
        APPLY_STAGES();
        #pragma unroll
        for (int i = 0; i < 16; ++i)
            *(float2*)(sb + addr[i]) = a[i];
        #pragma unroll
        for (int i = 0; i < 16; ++i) cmbreg[i] = cmbn[i];
        #pragma unroll
        for (int q = 0; q < 4; ++q) gidxr[q] = gidxn[q];
        nwr = nwn; rn = rnn;
    }

    // ---- final pass: reads + gates, measurement straight from registers ----
    float acc = 0.f;
    {
        __syncthreads();
        const unsigned rb = rn << 3;
        #pragma unroll
        for (int i = 0; i < 16; ++i) addr[i] = rb ^ cmbreg[i];
        #pragma unroll
        for (int i = 0; i < 16; ++i)
            a[i] = *(const float2*)(sb + addr[i]);
        APPLY_STAGES();

        // weight of amp at address rn^cmb_i: sign_w = par(rn&ms_w) ^ fmask_w[i]
        float A[16];
        #pragma unroll
        for (int i = 0; i < 16; ++i) A[i] = 0.f;
        #pragma unroll
        for (int w = 0; w < NQ; ++w) {
            float v = wl[w];
            unsigned p0 = __popc(rn & pp->ms[w]) & 1u;
            float vs = p0 ? -v : v;
            const unsigned fm = pp->fmask[w];
            #pragma unroll
            for (int i = 0; i < 16; ++i)
                A[i] += ((fm >> i) & 1u) ? -vs : vs;
        }
        #pragma unroll
        for (int i = 0; i < 16; ++i)
            acc = fmaf(fmaf(a[i].x, a[i].x, a[i].y * a[i].y), A[i], acc);
    }

    #pragma unroll
    for (int off = 32; off > 0; off >>= 1) acc += __shfl_down(acc, off, 64);
    if ((tid & 63) == 0) red[tid >> 6] = acc;
    __syncthreads();
    if (tid == 0) {
        float s2 = 0.f;
        #pragma unroll
        for (int i = 0; i < NWAVES; ++i) s2 += red[i];
        out[b] = s2 + bl[0];
    }
}

// ---- host-side GF(2) helpers ----
struct GF2Basis {
    unsigned piv[NQ];
    GF2Basis() { for (int i = 0; i < NQ; ++i) piv[i] = 0; }
    bool insert(unsigned v) {            // true iff rank increased
        for (int bb = NQ - 1; bb >= 0; --bb) {
            if (!((v >> bb) & 1)) continue;
            if (piv[bb]) v ^= piv[bb];
            else { piv[bb] = v; return true; }
        }
        return false;
    }
};

static inline int par16(unsigned v) { return __builtin_parity(v); }
static inline unsigned lcg_next(unsigned& s) { s = s * 1664525u + 1013904223u; return s >> 8; }

static unsigned gf_apply(const unsigned* C, unsigned v) {
    unsigned r = 0;
    while (v) { int j = __builtin_ctz(v); v &= v - 1; r ^= C[j]; }
    return r;
}

// C = columns of sigma; on success Ci = columns of sigma^{-1}
static bool gf_invert(const unsigned* C, unsigned* Ci) {
    unsigned rows[NQ], irows[NQ];
    for (int i = 0; i < NQ; ++i) {
        unsigned r = 0;
        for (int j = 0; j < NQ; ++j) r |= ((C[j] >> i) & 1u) << j;
        rows[i] = r; irows[i] = 1u << i;
    }
    for (int c = 0; c < NQ; ++c) {
        int p = -1;
        for (int r = c; r < NQ; ++r) if ((rows[r] >> c) & 1u) { p = r; break; }
        if (p < 0) return false;
        unsigned t = rows[p]; rows[p] = rows[c]; rows[c] = t;
        t = irows[p]; irows[p] = irows[c]; irows[c] = t;
        for (int r = 0; r < NQ; ++r)
            if (r != c && ((rows[r] >> c) & 1u)) { rows[r] ^= rows[c]; irows[r] ^= irows[c]; }
    }
    for (int j = 0; j < NQ; ++j) {
        unsigned col = 0;
        for (int i = 0; i < NQ; ++i) col |= ((irows[i] >> j) & 1u) << i;
        Ci[j] = col;
    }
    return true;
}

extern "C" void kernel_launch(void* const* d_in, const int* in_sizes, int n_in,
                              void* d_out, int out_size, void* d_ws, size_t ws_size,
                              hipStream_t stream) {
    const float* x  = (const float*)d_in[0];   // (B, 14)
    const float* qw = (const float*)d_in[1];   // (3, 14, 3)
    const float* wl = (const float*)d_in[2];   // (1, 14)
    const float* bl = (const float*)d_in[3];   // (1,)
    float* out = (float*)d_out;                // (B, 1)

    const int B = in_sizes[0] / NQ;

    // ---- build gate list in circuit order with (s,m) captured per gate ----
    // s[w] = selector row, m[w] = flip mask; par(s_i & m_j)=delta_ij at all
    // times (ring updates preserve duality of the CURRENT frame).
    unsigned gs[NL * NQ], gm[NL * NQ];
    int ggi[NL * NQ];
    unsigned s[NQ], m[NQ], msIdx[NQ];
    for (int w = 0; w < NQ; ++w) s[w] = m[w] = 1u << (NQ - 1 - w); // wire 0 = MSB
    int ng = 0;
    for (int l = 0; l < NL; ++l) {
        for (int w = 0; w < NQ; ++w) {
            gs[ng] = s[w]; gm[ng] = m[w]; ggi[ng] = l * NQ + w; ++ng;
        }
        int r = (l % (NQ - 1)) + 1;            // PennyLane ranges: 1,2,3
        for (int w = 0; w < NQ; ++w) {         // CNOT ring: control w, target (w+r)%NQ
            int c = w, t = (w + r) % NQ;
            s[t] ^= s[c];
            m[c] ^= m[t];
        }
    }
    for (int w = 0; w < NQ; ++w) msIdx[w] = s[w];

    // ---- greedy pack gates into passes (cross-layer mixing allowed) ----
    // A gate g may join the current pass iff:
    //  (a) biorthogonal with all pass members: par(s_g&m_k)=par(s_k&m_g)=0
    //  (b) commutes with every earlier-in-circuit, not-yet-applied gate h
    //  (c) m_g independent of the pass's flip-mask span
    // Worst case this degrades to layer-local 4/4/4/2 packing (<=12 passes);
    // for this circuit it yields 11 passes.
    struct Raw { unsigned rv[10], cmb[16]; unsigned char gidx[4], nw; } raw[MAXP];
    bool used[NL * NQ] = {false};
    int np = 0, remaining = ng;
    while (remaining > 0 && np < MAXP) {
        unsigned pss[4], pmm[4];
        int pgi[4], nw = 0;
        GF2Basis gf;
        for (int g = 0; g < ng && nw < 4; ++g) {
            if (used[g]) continue;
            bool ok = true;
            for (int k = 0; k < nw && ok; ++k)
                if (par16(gs[g] & pmm[k]) || par16(pss[k] & gm[g])) ok = false;
            for (int h = 0; h < g && ok; ++h)
                if (!used[h] && (par16(gs[g] & gm[h]) || par16(gs[h] & gm[g]))) ok = false;
            if (!ok) continue;
            GF2Basis trial = gf;
            if (!trial.insert(gm[g])) continue;
            gf = trial;
            pss[nw] = gs[g]; pmm[nw] = gm[g]; pgi[nw] = g; ++nw;
            used[g] = true; --remaining;
        }
        // pad to 4 independent masks; normalize pads so they don't flip the
        // real wires' logical bits
        unsigned mm[4], ss[4];
        for (int i = 0; i < nw; ++i) { mm[i] = pmm[i]; ss[i] = pss[i]; }
        for (int i = nw; i < 4; ++i) {
            unsigned cand = 0;
            for (int t = 0; t < NQ; ++t)
                if (gf.insert(1u << t)) { cand = 1u << t; break; }
            for (int j = 0; j < nw; ++j)
                if (par16(cand & ss[j])) cand ^= mm[j];
            mm[i] = cand; ss[i] = 0;
        }
        // complement basis (10 vecs), normalized to zero logical bits
        int nR = 0;
        for (int t = 0; t < NQ && nR < 10; ++t) {
            if (gf.insert(1u << t)) {
                unsigned v = 1u << t;
                for (int j = 0; j < nw; ++j)
                    if (par16(v & ss[j])) v ^= mm[j];
                raw[np].rv[nR++] = v;
            }
        }
        for (int idx = 0; idx < 16; ++idx) {
            unsigned c = 0;
            for (int q = 0; q < 4; ++q) if ((idx >> q) & 1) c ^= mm[q];
            raw[np].cmb[idx] = c;
        }
        for (int q = 0; q < 4; ++q)
            raw[np].gidx[q] = (unsigned char)(q < nw ? ggi[pgi[q]] : 0);
        raw[np].nw = (unsigned char)nw;
        ++np;
    }

    // ---- choose layout sigma: every pass's rep space must project with
    // rank 4 onto the bank-pair bits (addr mod 16) ----
    unsigned Cm[NQ], Ci[NQ];
    unsigned seed = 0x9E3779B9u;
    bool found = false;
    for (int tries = 0; tries < 5000 && !found; ++tries) {
        for (int j = 0; j < NQ; ++j) Cm[j] = lcg_next(seed) & (NSTATE - 1);
        if (!gf_invert(Cm, Ci)) continue;
        found = true;
        for (int p = 0; p < np && found; ++p) {
            unsigned piv[4] = {0, 0, 0, 0}; int npv = 0;
            for (int i = 0; i < 10; ++i) {
                unsigned w2 = gf_apply(Cm, raw[p].rv[i]);
                for (int bb = 0; bb < 4; ++bb)
                    if (((w2 >> bb) & 1u) && piv[bb]) w2 ^= piv[bb];
                if ((w2 & 15u) && npv < 4) { piv[__builtin_ctz(w2 & 15u)] = w2; ++npv; }
            }
            if (npv < 4) found = false;
        }
    }
    if (!found) {  // fallback: identity layout (correct, just slower)
        for (int j = 0; j < NQ; ++j) Cm[j] = 1u << j;
        gf_invert(Cm, Ci);
    }

    // ---- emit device params in ADDRESS space into the global table ----
    static ParamsG h_pg;                // static: stable across graph replays
    memset(&h_pg, 0, sizeof(h_pg));
    for (int p = 0; p < np; ++p) {
        unsigned u[10];
        for (int i = 0; i < 10; ++i) u[i] = gf_apply(Cm, raw[p].rv[i]);
        // order: 4 bank-pivot vectors first (they cover lane bits 0..3)
        unsigned piv[4] = {0, 0, 0, 0};
        int ord[10], npv = 0, rest[10], nrest = 0;
        for (int i = 0; i < 10; ++i) {
            unsigned w2 = u[i];
            for (int bb = 0; bb < 4; ++bb)
                if (((w2 >> bb) & 1u) && piv[bb]) w2 ^= piv[bb];
            if ((w2 & 15u) && npv < 4) { piv[__builtin_ctz(w2 & 15u)] = w2; ord[npv++] = i; }
            else rest[nrest++] = i;
        }
        int kk = 0;
        for (int i = 0; i < npv; ++i) h_pg.pass[p].R[kk++] = u[ord[i]];
        for (int i = 0; i < nrest; ++i) h_pg.pass[p].R[kk++] = u[rest[i]];
        for (int idx = 0; idx < 16; ++idx)
            h_pg.pass[p].cmb8[idx] = gf_apply(Cm, raw[p].cmb[idx]) << 3;
        for (int q = 0; q < 4; ++q) h_pg.pass[p].gidx[q] = raw[p].gidx[q];
        h_pg.pass[p].nw = raw[p].nw;
    }
    // measurement masks: par(sigma^{-1}(t) & ms) = par(t & sigma^{-T} ms)
    for (int w = 0; w < NQ; ++w) {
        unsigned msp = 0;
        for (int i = 0; i < NQ; ++i)
            msp |= (unsigned)(par16(Ci[i] & msIdx[w]) & 1) << i;
        h_pg.ms[w] = msp;
    }
    // combo-part parities of the FINAL pass (measurement runs from registers;
    // cmb8 is pre-shifted, ms is not -> compare in index space)
    for (int w = 0; w < NQ; ++w) {
        unsigned fm = 0;
        for (int i = 0; i < 16; ++i)
            fm |= (unsigned)(par16((h_pg.pass[np - 1].cmb8[i] >> 3) & h_pg.ms[w]) & 1) << i;
        h_pg.fmask[w] = fm;
    }

    ParamsG* d_pg = (ParamsG*)d_ws;
    hipMemcpyAsync(d_pg, &h_pg, sizeof(ParamsG), hipMemcpyHostToDevice, stream);
    qsim_kernel<<<dim3(B), dim3(BT), 0, stream>>>(x, qw, wl, bl, out, d_pg, np);
}

// Round 3
// 100.156 us; speedup vs baseline: 1.1396x; 1.0943x over previous
//
#include <hip/hip_runtime.h>
#include <string.h>

#define NQ 14
#define NSTATE (1 << NQ)       // 16384 amplitudes
#define NL 3
#define MAXP 12                // max table entries (init + gate passes)
#define BT 1024                // threads per block
#define NWAVES (BT / 64)

// Lazily-permuted simulation: CNOT rings folded into GF(2) index maps, and a
// global GF(2)-linear LDS layout sigma (amp p stored at address sigma(p)).
// sigma is chosen host-side so that EVERY pass's representative space
// projects with full rank 4 onto the bank-pair bits (addr mod 16).
// This version additionally exploits that LAYER 0 IS A PRODUCT STATE:
// before the first CNOT ring the state is  tensor_w (Rot_w RX_w |0>), so
// pass 0 initializes amplitudes analytically (39 cmul/thread, no reads)
// with groups aligned to wires 10..13 so the 16 amps factor, and only the
// 28 gates of layers 1-2 are simulated -> 7 gate passes instead of 11.
// Params live in a global table (d_ws) prefetched one pass ahead with
// vmcnt-domain loads (keeps the K-loop lgkm domain pure in-order DS).
struct PassG {
    unsigned cmb8[16];   // XOR combos of the 4 pair masks, pre-shifted <<3 (byte offsets)
    unsigned R[10];      // complement-basis images (tid -> group representative)
    unsigned gidx[4];    // gate table indices
    unsigned nw;         // real gates in this pass (0 for the init entry)
    unsigned pad;        // -> 32 uints = 128 B per pass
};
struct ParamsG {
    PassG pass[MAXP];
    unsigned ms[NQ];      // final Z_w selector masks (address space)
    unsigned fmask[NQ];   // bit i = par(cmb_last[i] & ms[w])
    unsigned initIW[10];  // bit w = physical-bit_w contribution of R0[j] (j=tid bit)
};

struct C2x2 { float2 m[2][2]; };

__device__ __forceinline__ float2 cmul(float2 a, float2 b) {
    return make_float2(a.x * b.x - a.y * b.y, a.x * b.y + a.y * b.x);
}
__device__ __forceinline__ float2 cmac(float2 acc, float2 a, float2 b) {
    acc.x = fmaf(a.x, b.x, fmaf(-a.y, b.y, acc.x));
    acc.y = fmaf(a.x, b.y, fmaf(a.y, b.x, acc.y));
    return acc;
}

// PennyLane Rot(phi,theta,omega) = RZ(omega) RY(theta) RZ(phi)
__device__ __forceinline__ C2x2 rot_gate(const float* qp) {
    float phi = qp[0], th = qp[1], om = qp[2];
    float ct, stt; __sincosf(0.5f * th, &stt, &ct);
    float sa, ca; __sincosf(0.5f * (phi + om), &sa, &ca);
    float sb, cb; __sincosf(0.5f * (phi - om), &sb, &cb);
    C2x2 G;
    G.m[0][0] = make_float2(ca * ct, -sa * ct);
    G.m[0][1] = make_float2(-cb * stt, -sb * stt);
    G.m[1][0] = make_float2(cb * stt, -sb * stt);
    G.m[1][1] = make_float2(ca * ct, sa * ct);
    return G;
}

// G := G * RX(ang)   (RX applied first to the state)
__device__ __forceinline__ C2x2 fuse_rx(C2x2 G, float ang) {
    float sh, ch; __sincosf(0.5f * ang, &sh, &ch);
    float2 c = make_float2(ch, 0.f), is = make_float2(0.f, -sh);
    C2x2 R;
    #pragma unroll
    for (int i = 0; i < 2; ++i) {
        R.m[i][0] = cmac(cmul(G.m[i][0], c), G.m[i][1], is);
        R.m[i][1] = cmac(cmul(G.m[i][1], c), G.m[i][0], is);
    }
    return R;
}

// load one pass's params into registers (global loads only -> vmcnt domain)
__device__ __forceinline__ void load_pass(const PassG* __restrict__ p, int tid,
        unsigned cmb[16], unsigned gidx[4], unsigned& nw, unsigned& r)
{
    const uint4* c4 = (const uint4*)p->cmb8;
    uint4 u0 = c4[0], u1 = c4[1], u2 = c4[2], u3 = c4[3];
    cmb[0] = u0.x; cmb[1] = u0.y; cmb[2]  = u0.z; cmb[3]  = u0.w;
    cmb[4] = u1.x; cmb[5] = u1.y; cmb[6]  = u1.z; cmb[7]  = u1.w;
    cmb[8] = u2.x; cmb[9] = u2.y; cmb[10] = u2.z; cmb[11] = u2.w;
    cmb[12] = u3.x; cmb[13] = u3.y; cmb[14] = u3.z; cmb[15] = u3.w;
    unsigned rr = 0;
    #pragma unroll
    for (int j = 0; j < 10; ++j)
        rr ^= ((tid >> j) & 1) ? p->R[j] : 0u;
    r = rr;
    #pragma unroll
    for (int q = 0; q < 4; ++q) gidx[q] = p->gidx[q];
    nw = p->nw;
}

// staged 2x2 gate applications on a[16] using register params gidxr/nwr
#define APPLY_STAGES()                                                      \
    {                                                                       \
        _Pragma("unroll")                                                   \
        for (int q = 0; q < 4; ++q) {                                       \
            if (q < (int)nwr) {    /* wave-uniform branch */                \
                const int gi = (int)gidxr[q] * 4;                           \
                float2 g00 = gbuf[gi + 0], g01 = gbuf[gi + 1];              \
                float2 g10 = gbuf[gi + 2], g11 = gbuf[gi + 3];              \
                _Pragma("unroll")                                           \
                for (int i = 0; i < 16; ++i) {                              \
                    if (!((i >> q) & 1)) {                                  \
                        const int i1 = i | (1 << q);                        \
                        float2 a0 = a[i], a1 = a[i1];                       \
                        float2 n0 = cmac(cmul(g00, a0), g01, a1);           \
                        float2 n1 = cmac(cmul(g10, a0), g11, a1);           \
                        a[i] = n0; a[i1] = n1;                              \
                    }                                                       \
                }                                                           \
            }                                                               \
        }                                                                   \
    }

__global__ __launch_bounds__(BT) void qsim_kernel(
    const float* __restrict__ x, const float* __restrict__ qw,
    const float* __restrict__ wl, const float* __restrict__ bl,
    float* __restrict__ out, const ParamsG* __restrict__ pp, int np)
{
    __shared__ float2 st[NSTATE];          // 128 KB state
    __shared__ float2 gbuf[NL * NQ * 4];   // 42 precomputed 2x2 gates
    __shared__ float2 ubuf[NQ][2];         // per-wire layer-0 2-vectors u_w
    __shared__ float red[NWAVES];

    const int tid = threadIdx.x;
    const int b = blockIdx.x;

    // precompute all 2x2 gates once (layer 0 fuses the RX embedding);
    // layer-0 gates additionally publish u_w = G*(1,0)^T for the init
    if (tid < NL * NQ) {
        int l = tid / NQ, w = tid % NQ;
        C2x2 G = rot_gate(qw + tid * 3);
        if (l == 0) {
            G = fuse_rx(G, x[b * NQ + w]);
            ubuf[w][0] = G.m[0][0];
            ubuf[w][1] = G.m[1][0];
        }
        gbuf[tid * 4 + 0] = G.m[0][0];
        gbuf[tid * 4 + 1] = G.m[0][1];
        gbuf[tid * 4 + 2] = G.m[1][0];
        gbuf[tid * 4 + 3] = G.m[1][1];
    }

    char* sb = (char*)st;
    float2 a[16];
    unsigned addr[16];
    unsigned cmbreg[16], gidxr[4], nwr, rn;

    load_pass(&pp->pass[0], tid, cmbreg, gidxr, nwr, rn);

    // physical bits (wires 0..9) of this thread's init rep: GF(2)-linear in tid
    unsigned b0 = 0;
    #pragma unroll
    for (int j = 0; j < 10; ++j)
        b0 ^= ((tid >> j) & 1) ? pp->initIW[j] : 0u;

    __syncthreads();   // gbuf + ubuf ready

    // ---- pass 0: analytic product-state init (layer 0 never entangles) ----
    // amp(rep ^ cmb_i) = [prod_{w=0..9} u_w[bit_w(rep)]] * prod_{q} u_{10+q}[i_q]
    {
        const unsigned rb = rn << 3;
        float2 c = ubuf[0][b0 & 1];
        #pragma unroll
        for (int w = 1; w < 10; ++w)
            c = cmul(c, ubuf[w][(b0 >> w) & 1]);
        a[0] = cmul(c, ubuf[10][0]);
        a[1] = cmul(c, ubuf[10][1]);
        #pragma unroll
        for (int i = 0; i < 2; ++i) {
            a[2 + i] = cmul(a[i], ubuf[11][1]);
            a[i]     = cmul(a[i], ubuf[11][0]);
        }
        #pragma unroll
        for (int i = 0; i < 4; ++i) {
            a[4 + i] = cmul(a[i], ubuf[12][1]);
            a[i]     = cmul(a[i], ubuf[12][0]);
        }
        #pragma unroll
        for (int i = 0; i < 8; ++i) {
            a[8 + i] = cmul(a[i], ubuf[13][1]);
            a[i]     = cmul(a[i], ubuf[13][0]);
        }
        #pragma unroll
        for (int i = 0; i < 16; ++i)
            *(float2*)(sb + (rb ^ cmbreg[i])) = a[i];   // this IS the state init
    }

    load_pass(&pp->pass[1], tid, cmbreg, gidxr, nwr, rn);

    #pragma unroll 1
    for (int ps = 1; ps < np - 1; ++ps) {
        __syncthreads();   // previous pass's writes visible
        const unsigned rb = rn << 3;
        #pragma unroll
        for (int i = 0; i < 16; ++i) addr[i] = rb ^ cmbreg[i];
        #pragma unroll
        for (int i = 0; i < 16; ++i)
            a[i] = *(const float2*)(sb + addr[i]);
        // prefetch next pass's params during this pass's compute
        // (global loads -> vmcnt, cannot force lgkmcnt drains on the ds_reads)
        unsigned cmbn[16], gidxn[4], nwn, rnn;
        load_pass(&pp->pass[ps + 1], tid, cmbn, gidxn, nwn, rnn);
        APPLY_STAGES();
        #pragma unroll
        for (int i = 0; i < 16; ++i)
            *(float2*)(sb + addr[i]) = a[i];
        #pragma unroll
        for (int i = 0; i < 16; ++i) cmbreg[i] = cmbn[i];
        #pragma unroll
        for (int q = 0; q < 4; ++q) gidxr[q] = gidxn[q];
        nwr = nwn; rn = rnn;
    }

    // ---- final pass: reads + gates, measurement straight from registers ----
    float acc = 0.f;
    {
        __syncthreads();
        const unsigned rb = rn << 3;
        #pragma unroll
        for (int i = 0; i < 16; ++i) addr[i] = rb ^ cmbreg[i];
        #pragma unroll
        for (int i = 0; i < 16; ++i)
            a[i] = *(const float2*)(sb + addr[i]);
        APPLY_STAGES();

        // weight of amp at address rn^cmb_i: sign_w = par(rn&ms_w) ^ fmask_w[i]
        float A[16];
        #pragma unroll
        for (int i = 0; i < 16; ++i) A[i] = 0.f;
        #pragma unroll
        for (int w = 0; w < NQ; ++w) {
            float v = wl[w];
            unsigned p0 = __popc(rn & pp->ms[w]) & 1u;
            float vs = p0 ? -v : v;
            const unsigned fm = pp->fmask[w];
            #pragma unroll
            for (int i = 0; i < 16; ++i)
                A[i] += ((fm >> i) & 1u) ? -vs : vs;
        }
        #pragma unroll
        for (int i = 0; i < 16; ++i)
            acc = fmaf(fmaf(a[i].x, a[i].x, a[i].y * a[i].y), A[i], acc);
    }

    #pragma unroll
    for (int off = 32; off > 0; off >>= 1) acc += __shfl_down(acc, off, 64);
    if ((tid & 63) == 0) red[tid >> 6] = acc;
    __syncthreads();
    if (tid == 0) {
        float s2 = 0.f;
        #pragma unroll
        for (int i = 0; i < NWAVES; ++i) s2 += red[i];
        out[b] = s2 + bl[0];
    }
}

// ---- host-side GF(2) helpers ----
struct GF2Basis {
    unsigned piv[NQ];
    GF2Basis() { for (int i = 0; i < NQ; ++i) piv[i] = 0; }
    bool insert(unsigned v) {            // true iff rank increased
        for (int bb = NQ - 1; bb >= 0; --bb) {
            if (!((v >> bb) & 1)) continue;
            if (piv[bb]) v ^= piv[bb];
            else { piv[bb] = v; return true; }
        }
        return false;
    }
};

static inline int par16(unsigned v) { return __builtin_parity(v); }
static inline unsigned lcg_next(unsigned& s) { s = s * 1664525u + 1013904223u; return s >> 8; }

static unsigned gf_apply(const unsigned* C, unsigned v) {
    unsigned r = 0;
    while (v) { int j = __builtin_ctz(v); v &= v - 1; r ^= C[j]; }
    return r;
}

// C = columns of sigma; on success Ci = columns of sigma^{-1}
static bool gf_invert(const unsigned* C, unsigned* Ci) {
    unsigned rows[NQ], irows[NQ];
    for (int i = 0; i < NQ; ++i) {
        unsigned r = 0;
        for (int j = 0; j < NQ; ++j) r |= ((C[j] >> i) & 1u) << j;
        rows[i] = r; irows[i] = 1u << i;
    }
    for (int c = 0; c < NQ; ++c) {
        int p = -1;
        for (int r = c; r < NQ; ++r) if ((rows[r] >> c) & 1u) { p = r; break; }
        if (p < 0) return false;
        unsigned t = rows[p]; rows[p] = rows[c]; rows[c] = t;
        t = irows[p]; irows[p] = irows[c]; irows[c] = t;
        for (int r = 0; r < NQ; ++r)
            if (r != c && ((rows[r] >> c) & 1u)) { rows[r] ^= rows[c]; irows[r] ^= irows[c]; }
    }
    for (int j = 0; j < NQ; ++j) {
        unsigned col = 0;
        for (int i = 0; i < NQ; ++i) col |= ((irows[i] >> j) & 1u) << i;
        Ci[j] = col;
    }
    return true;
}

extern "C" void kernel_launch(void* const* d_in, const int* in_sizes, int n_in,
                              void* d_out, int out_size, void* d_ws, size_t ws_size,
                              hipStream_t stream) {
    const float* x  = (const float*)d_in[0];   // (B, 14)
    const float* qw = (const float*)d_in[1];   // (3, 14, 3)
    const float* wl = (const float*)d_in[2];   // (1, 14)
    const float* bl = (const float*)d_in[3];   // (1,)
    float* out = (float*)d_out;                // (B, 1)

    const int B = in_sizes[0] / NQ;

    // ---- build gate list (LAYERS 1-2 ONLY; layer 0 = analytic init) in
    // circuit order with (s,m) captured per gate. Rings (incl. layer 0's)
    // are folded into the frame in circuit order.
    unsigned gs[NL * NQ], gm[NL * NQ];
    int ggi[NL * NQ];
    unsigned s[NQ], m[NQ], msIdx[NQ];
    for (int w = 0; w < NQ; ++w) s[w] = m[w] = 1u << (NQ - 1 - w); // wire 0 = MSB
    int ng = 0;
    for (int l = 0; l < NL; ++l) {
        if (l > 0) {
            for (int w = 0; w < NQ; ++w) {
                gs[ng] = s[w]; gm[ng] = m[w]; ggi[ng] = l * NQ + w; ++ng;
            }
        }
        int r = (l % (NQ - 1)) + 1;            // PennyLane ranges: 1,2,3
        for (int w = 0; w < NQ; ++w) {         // CNOT ring: control w, target (w+r)%NQ
            int c = w, t = (w + r) % NQ;
            s[t] ^= s[c];
            m[c] ^= m[t];
        }
    }
    for (int w = 0; w < NQ; ++w) msIdx[w] = s[w];

    struct Raw { unsigned rv[10], cmb[16]; unsigned char gidx[4], nw; } raw[MAXP];

    // ---- entry 0: init group aligned to wires 10..13 (index space units) ----
    {
        unsigned mm[4];
        for (int q = 0; q < 4; ++q) mm[q] = 1u << (3 - q);    // wire 10+q
        for (int j = 0; j < 10; ++j) raw[0].rv[j] = 1u << (13 - j); // wires 0..9
        for (int idx = 0; idx < 16; ++idx) {
            unsigned c = 0;
            for (int q = 0; q < 4; ++q) if ((idx >> q) & 1) c ^= mm[q];
            raw[0].cmb[idx] = c;
        }
        for (int q = 0; q < 4; ++q) raw[0].gidx[q] = 0;
        raw[0].nw = 0;
    }

    // ---- greedy pack the 28 gates into passes (cross-layer mixing) ----
    // A gate g may join the current pass iff:
    //  (a) biorthogonal with all pass members: par(s_g&m_k)=par(s_k&m_g)=0
    //  (b) commutes with every earlier-in-circuit, not-yet-applied gate h
    //  (c) m_g independent of the pass's flip-mask span
    // 28 gates -> 7 passes here (worst case 8).
    bool used[NL * NQ] = {false};
    int np = 1, remaining = ng;
    while (remaining > 0 && np < MAXP) {
        unsigned pss[4], pmm[4];
        int pgi[4], nw = 0;
        GF2Basis gf;
        for (int g = 0; g < ng && nw < 4; ++g) {
            if (used[g]) continue;
            bool ok = true;
            for (int k = 0; k < nw && ok; ++k)
                if (par16(gs[g] & pmm[k]) || par16(pss[k] & gm[g])) ok = false;
            for (int h = 0; h < g && ok; ++h)
                if (!used[h] && (par16(gs[g] & gm[h]) || par16(gs[h] & gm[g]))) ok = false;
            if (!ok) continue;
            GF2Basis trial = gf;
            if (!trial.insert(gm[g])) continue;
            gf = trial;
            pss[nw] = gs[g]; pmm[nw] = gm[g]; pgi[nw] = g; ++nw;
            used[g] = true; --remaining;
        }
        // pad to 4 independent masks; normalize pads so they don't flip the
        // real wires' logical bits
        unsigned mm[4], ss[4];
        for (int i = 0; i < nw; ++i) { mm[i] = pmm[i]; ss[i] = pss[i]; }
        for (int i = nw; i < 4; ++i) {
            unsigned cand = 0;
            for (int t = 0; t < NQ; ++t)
                if (gf.insert(1u << t)) { cand = 1u << t; break; }
            for (int j = 0; j < nw; ++j)
                if (par16(cand & ss[j])) cand ^= mm[j];
            mm[i] = cand; ss[i] = 0;
        }
        // complement basis (10 vecs), normalized to zero logical bits
        int nR = 0;
        for (int t = 0; t < NQ && nR < 10; ++t) {
            if (gf.insert(1u << t)) {
                unsigned v = 1u << t;
                for (int j = 0; j < nw; ++j)
                    if (par16(v & ss[j])) v ^= mm[j];
                raw[np].rv[nR++] = v;
            }
        }
        for (int idx = 0; idx < 16; ++idx) {
            unsigned c = 0;
            for (int q = 0; q < 4; ++q) if ((idx >> q) & 1) c ^= mm[q];
            raw[np].cmb[idx] = c;
        }
        for (int q = 0; q < 4; ++q)
            raw[np].gidx[q] = (unsigned char)(q < nw ? ggi[pgi[q]] : 0);
        raw[np].nw = (unsigned char)nw;
        ++np;
    }

    // ---- choose layout sigma: every entry's rep space (incl. init) must
    // project with full rank 4 onto the bank-pair bits (addr mod 16) ----
    unsigned Cm[NQ], Ci[NQ];
    unsigned seed = 0x9E3779B9u;
    bool found = false;
    for (int tries = 0; tries < 5000 && !found; ++tries) {
        for (int j = 0; j < NQ; ++j) Cm[j] = lcg_next(seed) & (NSTATE - 1);
        if (!gf_invert(Cm, Ci)) continue;
        found = true;
        for (int p = 0; p < np && found; ++p) {
            unsigned piv[4] = {0, 0, 0, 0}; int npv = 0;
            for (int i = 0; i < 10; ++i) {
                unsigned w2 = gf_apply(Cm, raw[p].rv[i]);
                for (int bb = 0; bb < 4; ++bb)
                    if (((w2 >> bb) & 1u) && piv[bb]) w2 ^= piv[bb];
                if ((w2 & 15u) && npv < 4) { piv[__builtin_ctz(w2 & 15u)] = w2; ++npv; }
            }
            if (npv < 4) found = false;
        }
    }
    if (!found) {  // fallback: identity layout (correct, just slower)
        for (int j = 0; j < NQ; ++j) Cm[j] = 1u << j;
        gf_invert(Cm, Ci);
    }

    // ---- emit device params in ADDRESS space into the global table ----
    static ParamsG h_pg;                // static: stable across graph replays
    memset(&h_pg, 0, sizeof(h_pg));
    for (int p = 0; p < np; ++p) {
        unsigned u[10];
        for (int i = 0; i < 10; ++i) u[i] = gf_apply(Cm, raw[p].rv[i]);
        // order: 4 bank-pivot vectors first (they cover lane bits 0..3)
        unsigned piv[4] = {0, 0, 0, 0};
        int ord[10], npv = 0, rest[10], nrest = 0;
        for (int i = 0; i < 10; ++i) {
            unsigned w2 = u[i];
            for (int bb = 0; bb < 4; ++bb)
                if (((w2 >> bb) & 1u) && piv[bb]) w2 ^= piv[bb];
            if ((w2 & 15u) && npv < 4) { piv[__builtin_ctz(w2 & 15u)] = w2; ord[npv++] = i; }
            else rest[nrest++] = i;
        }
        int kk = 0;
        for (int i = 0; i < npv; ++i) h_pg.pass[p].R[kk++] = u[ord[i]];
        for (int i = 0; i < nrest; ++i) h_pg.pass[p].R[kk++] = u[rest[i]];
        for (int idx = 0; idx < 16; ++idx)
            h_pg.pass[p].cmb8[idx] = gf_apply(Cm, raw[p].cmb[idx]) << 3;
        for (int q = 0; q < 4; ++q) h_pg.pass[p].gidx[q] = raw[p].gidx[q];
        h_pg.pass[p].nw = raw[p].nw;
    }
    // measurement masks: par(sigma^{-1}(t) & ms) = par(t & sigma^{-T} ms)
    for (int w = 0; w < NQ; ++w) {
        unsigned msp = 0;
        for (int i = 0; i < NQ; ++i)
            msp |= (unsigned)(par16(Ci[i] & msIdx[w]) & 1) << i;
        h_pg.ms[w] = msp;
    }
    // combo-part parities of the FINAL pass (measurement runs from registers;
    // cmb8 is pre-shifted, ms is in address space -> compare unshifted)
    for (int w = 0; w < NQ; ++w) {
        unsigned fm = 0;
        for (int i = 0; i < 16; ++i)
            fm |= (unsigned)(par16((h_pg.pass[np - 1].cmb8[i] >> 3) & h_pg.ms[w]) & 1) << i;
        h_pg.fmask[w] = fm;
    }
    // init physical-bit tables: bit_w(sigma^{-1}(a)) = par(a & t_w), with
    // t_w = sigma^{-T}(unit of wire w); IW[j] packs par(R0[j] & t_w) at bit w.
    {
        unsigned tmask[NQ];
        for (int w = 0; w < NQ; ++w) {
            unsigned t = 0;
            for (int i = 0; i < NQ; ++i)
                t |= (unsigned)((Ci[i] >> (NQ - 1 - w)) & 1u) << i;
            tmask[w] = t;
        }
        for (int j = 0; j < 10; ++j) {
            unsigned iw = 0;
            for (int w = 0; w < NQ; ++w)
                iw |= (unsigned)(par16(h_pg.pass[0].R[j] & tmask[w]) & 1) << w;
            h_pg.initIW[j] = iw;
        }
    }

    ParamsG* d_pg = (ParamsG*)d_ws;
    hipMemcpyAsync(d_pg, &h_pg, sizeof(ParamsG), hipMemcpyHostToDevice, stream);
    qsim_kernel<<<dim3(B), dim3(BT), 0, stream>>>(x, qw, wl, bl, out, d_pg, np);
}